// Round 1
// baseline (790.593 us; speedup 1.0000x reference)
//
#include <hip/hip_runtime.h>
#include <hip/hip_bf16.h>

#define V_ 262144
#define B_ 4
#define C_ 16
#define F_ 64
#define K_ 100
#define CAP_ 8192

// ---- ws layout (bytes) ----
// weights: B*V*4   = 4194304 @ 0
// labels : B*V*1   = 1048576 @ 4194304
// zero-region start @ 5242880:
//   hist : B*2048*4 = 32768  @ 5242880
//   cnt  : 16*4     = 64     @ 5275648
//   sums : 1024*4   = 4096   @ 5275712
//   ccnt : B*4      = 16     @ 5279808
// thresh : B*4      = 16     @ 5279824
// cval   : B*CAP*4  = 131072 @ 5279840
// cidx   : B*CAP*4  = 131072 @ 5410912
#define OFF_WEIGHTS 0
#define OFF_LABELS  4194304
#define OFF_ZERO    5242880
#define OFF_HIST    5242880
#define OFF_CNT     5275648
#define OFF_SUMS    5275712
#define OFF_CCNT    5279808
#define ZERO_BYTES  36944
#define OFF_THRESH  5279824
#define OFF_CVAL    5279840
#define OFF_CIDX    5410912

#define ASYNC_COPY16(gsrc, ldst) \
  __builtin_amdgcn_global_load_lds((const __attribute__((address_space(1))) unsigned int*)(gsrc), \
                                   (__attribute__((address_space(3))) unsigned int*)(ldst), 16, 0, 0)

// K1: weights = prod_c proba; labels = argmax_c y; class counts; topk histogram.
// grid (V/1024, B), block 256, 4 voxels/thread.
__global__ __launch_bounds__(256) void k_stream(const float* __restrict__ proba,
                                                const float* __restrict__ y,
                                                float* __restrict__ weights,
                                                unsigned char* __restrict__ labels,
                                                int* __restrict__ hist,
                                                int* __restrict__ cnt)
{
    const int b = blockIdx.y;
    const int tid = threadIdx.x;
    const int v0 = (blockIdx.x * 256 + tid) * 4;

    __shared__ int lhist[2048];
    __shared__ int lcnt[16];
    for (int i = tid; i < 2048; i += 256) lhist[i] = 0;
    if (tid < 16) lcnt[tid] = 0;
    __syncthreads();

    const float* pb = proba + ((size_t)b * C_) * V_ + v0;
    const float* yb = y     + ((size_t)b * C_) * V_ + v0;

    float4 w = *(const float4*)(pb);
    for (int c = 1; c < C_; c++) {
        float4 p = *(const float4*)(pb + (size_t)c * V_);
        w.x *= p.x; w.y *= p.y; w.z *= p.z; w.w *= p.w;
    }
    *(float4*)(weights + (size_t)b * V_ + v0) = w;

    int lab0 = 0, lab1 = 0, lab2 = 0, lab3 = 0;
    for (int c = 0; c < C_; c++) {
        float4 yv = *(const float4*)(yb + (size_t)c * V_);
        if (yv.x > 0.f) lab0 = c;
        if (yv.y > 0.f) lab1 = c;
        if (yv.z > 0.f) lab2 = c;
        if (yv.w > 0.f) lab3 = c;
    }
    uchar4 lb = make_uchar4((unsigned char)lab0, (unsigned char)lab1,
                            (unsigned char)lab2, (unsigned char)lab3);
    *(uchar4*)(labels + (size_t)b * V_ + v0) = lb;

    float wv[4] = {w.x, w.y, w.z, w.w};
    int   lv[4] = {lab0, lab1, lab2, lab3};
    for (int j = 0; j < 4; j++) {
        atomicAdd(&lcnt[lv[j]], 1);
        unsigned bits = __float_as_uint(wv[j]);
        atomicAdd(&lhist[bits >> 21], 1);
    }
    __syncthreads();
    if (tid < 16) atomicAdd(&cnt[tid], lcnt[tid]);
    for (int i = tid; i < 2048; i += 256)
        if (lhist[i]) atomicAdd(&hist[b * 2048 + i], lhist[i]);
}

// K2: sums[c][f] += emb[b][f][v] grouped by label. Transposed-tile layout:
// stage emb[64f][256v] via global_load_lds (row = 1024B = one wave write, pad after),
// lane=f, wave-uniform voxel => conflict-free LDS atomics (banks = lane%32).
__global__ __launch_bounds__(256) void k_sums(const float* __restrict__ emb,
                                              const unsigned char* __restrict__ labels,
                                              float* __restrict__ sums)
{
    __shared__ float tile[64 * 260];   // row stride 260 floats (1040B, 16B-aligned)
    __shared__ float acc[1024];        // [c][f]
    __shared__ unsigned int lab4[64];

    const int tid = threadIdx.x;
    const int lane = tid & 63;
    const int w = tid >> 6;

    for (int i = tid; i < 1024; i += 256) acc[i] = 0.f;

    const int chunksTotal = (B_ * V_) / 256;   // 4096
    for (int g = blockIdx.x; g < chunksTotal; g += gridDim.x) {
        const int b = g >> 10;              // 1024 chunks per batch
        const int v0 = (g & 1023) << 8;
        __syncthreads();   // protect tile/lab4 from previous iteration's readers (and acc init)

        if (tid < 64)
            lab4[tid] = *(const unsigned int*)(labels + (size_t)b * V_ + v0 + tid * 4);

        // each wave stages 16 rows (f = w*16 + r), 256 floats = 1024B per row
        for (int r = 0; r < 16; r++) {
            const int f = (w << 4) + r;
            const float* src = emb + (((size_t)b << 6) + f) * V_ + v0 + (lane << 2);
            ASYNC_COPY16(src, &tile[f * 260]);
        }
        __syncthreads();   // drains vmcnt (DMA) before reads

        // wave w handles local voxels [w*64, w*64+64)
        for (int gp = 0; gp < 16; gp++) {
            const int vl = (w << 6) + (gp << 2);
            float4 vals = *(const float4*)&tile[lane * 260 + vl];
            unsigned int lu = lab4[vl >> 2];
            atomicAdd(&acc[((lu      ) & 0xff) * 64 + lane], vals.x);
            atomicAdd(&acc[((lu >>  8) & 0xff) * 64 + lane], vals.y);
            atomicAdd(&acc[((lu >> 16) & 0xff) * 64 + lane], vals.z);
            atomicAdd(&acc[((lu >> 24)       ) * 64 + lane], vals.w);
        }
    }
    __syncthreads();
    for (int i = tid; i < 1024; i += 256) atomicAdd(&sums[i], acc[i]);
}

// K3: per-batch suffix scan of 2048-bin histogram -> threshold bin T:
// T = max bin s.t. #(values with bin' >= T) >= K.
__global__ __launch_bounds__(256) void k_scan(const int* __restrict__ hist,
                                              int* __restrict__ thresh)
{
    const int b = blockIdx.x, tid = threadIdx.x;
    __shared__ int part[256];
    __shared__ int suf[257];
    const int* h = hist + b * 2048;
    int loc[8]; int s = 0;
    for (int i = 0; i < 8; i++) { loc[i] = h[tid * 8 + i]; s += loc[i]; }
    part[tid] = s;
    __syncthreads();
    if (tid == 0) {
        suf[256] = 0;
        for (int t = 255; t >= 0; t--) suf[t] = suf[t + 1] + part[t];
    }
    __syncthreads();
    int cg[9];
    cg[8] = suf[tid + 1];
    for (int i = 7; i >= 0; i--) cg[i] = cg[i + 1] + loc[i];
    for (int i = 0; i < 8; i++)
        if (cg[i] >= K_ && cg[i + 1] < K_) thresh[b] = tid * 8 + i;
}

// K4: collect candidates with bin >= T into per-batch buffers.
__global__ __launch_bounds__(256) void k_collect(const float* __restrict__ weights,
                                                 const int* __restrict__ thresh,
                                                 int* __restrict__ ccnt,
                                                 float* __restrict__ cval,
                                                 int* __restrict__ cidx)
{
    const int b = blockIdx.y;
    const int v = (blockIdx.x * 256 + threadIdx.x) * 4;
    const unsigned T = (unsigned)thresh[b];
    float4 w = *(const float4*)(weights + (size_t)b * V_ + v);
    float wv[4] = {w.x, w.y, w.z, w.w};
    for (int j = 0; j < 4; j++) {
        unsigned bits = __float_as_uint(wv[j]);
        if ((bits >> 21) >= T) {
            int p = atomicAdd(&ccnt[b], 1);
            if (p < CAP_) {
                cval[b * CAP_ + p] = wv[j];
                cidx[b * CAP_ + p] = v + j;
            }
        }
    }
}

// K5: exact top-K select (rank over candidates, ties -> lower index), gather he/hec,
// build avg, compute the pairwise contrastive loss. One block per batch.
__global__ __launch_bounds__(256) void k_final(const float* __restrict__ emb,
                                               const unsigned char* __restrict__ labels,
                                               const float* __restrict__ sums,
                                               const int* __restrict__ cnt,
                                               const int* __restrict__ ccnt,
                                               const float* __restrict__ cval,
                                               const int* __restrict__ cidx,
                                               float* __restrict__ out)
{
    const int b = blockIdx.x, tid = threadIdx.x;
    __shared__ float avg[1024];       // [c][f]
    __shared__ float ec[K_ * 64];     // exp(logit at own class)
    __shared__ float Ssum[K_ * 64];   // sum_c exp(logit)
    __shared__ float lsum[K_];
    __shared__ int selIdx[K_];
    __shared__ int selLab[K_];
    __shared__ int nk[16];
    __shared__ int lists[16 * K_];
    __shared__ int ofs[17];
    __shared__ float red[256];

    for (int i = tid; i < 1024; i += 256) {
        int c = i >> 6;
        float cn = (float)cnt[c];
        avg[i] = (cn > 0.f) ? 0.9f * sums[i] / fmaxf(cn, 1.f) : 0.f;
    }
    if (tid < K_) { lsum[tid] = 0.f; selIdx[tid] = 0; }
    if (tid < 16) nk[tid] = 0;

    int M = ccnt[b]; if (M > CAP_) M = CAP_;
    const float* cv = cval + b * CAP_;
    const int*   ci = cidx + b * CAP_;
    for (int i = tid; i < M; i += 256) {
        float v = cv[i]; int id = ci[i];
        int rank = 0;
        for (int j = 0; j < M; j++) {
            float vj = cv[j];
            rank += (vj > v) || (vj == v && ci[j] < id);
        }
        if (rank < K_) selIdx[rank] = id;
    }
    __syncthreads();
    for (int i = tid; i < K_; i += 256) selLab[i] = labels[(size_t)b * V_ + selIdx[i]];
    __syncthreads();
    if (tid == 0) {
        for (int i = 0; i < K_; i++) { int c = selLab[i]; lists[c * K_ + nk[c]] = i; nk[c]++; }
        int o = 0;
        for (int c = 0; c < 16; c++) { ofs[c] = o; o += nk[c] * nk[c]; }
        ofs[16] = o;
    }
    __syncthreads();

    // ec, S, lsum
    for (int e = tid; e < K_ * 64; e += 256) {
        int k = e >> 6, f = e & 63;
        float h = emb[(((size_t)b << 6) + f) * V_ + selIdx[k]];
        int lab = selLab[k];
        float s = 0.f, ev = 0.f, lvv = 0.f;
        for (int c = 0; c < 16; c++) {
            float l = h * avg[(c << 6) + f] / 0.1f;
            float x = expf(l);
            s += x;
            if (c == lab) { ev = x; lvv = l; }
        }
        ec[e] = ev; Ssum[e] = s;
        atomicAdd(&lsum[k], lvv);
    }
    __syncthreads();

    const int P = ofs[16];
    float accv = 0.f;
    for (int p = tid; p < P; p += 256) {
        int c = 0;
        while (p >= ofs[c + 1]) c++;
        int loc = p - ofs[c];
        int n = nk[c];
        int i = lists[c * K_ + loc / n];
        int j = lists[c * K_ + loc % n];
        const float* eci = &ec[i << 6];
        const float* ecj = &ec[j << 6];
        const float* sj  = &Ssum[j << 6];
        float s = 0.f;
        for (int f = 0; f < 64; f++) s += logf(eci[f] + sj[f] - ecj[f]);
        accv += s / ((float)n * (float)n * 64.f);
    }
    for (int i2 = tid; i2 < K_; i2 += 256) {
        int c = selLab[i2];
        accv -= lsum[i2] / ((float)nk[c] * 64.f);
    }
    red[tid] = accv;
    __syncthreads();
    for (int s2 = 128; s2 > 0; s2 >>= 1) {
        if (tid < s2) red[tid] += red[tid + s2];
        __syncthreads();
    }
    if (tid == 0) atomicAdd(out, -red[0] / (float)B_);
}

extern "C" void kernel_launch(void* const* d_in, const int* in_sizes, int n_in,
                              void* d_out, int out_size, void* d_ws, size_t ws_size,
                              hipStream_t stream) {
    const float* proba = (const float*)d_in[0];
    const float* y     = (const float*)d_in[1];
    const float* emb   = (const float*)d_in[2];
    char* ws = (char*)d_ws;

    float* weights        = (float*)(ws + OFF_WEIGHTS);
    unsigned char* labels = (unsigned char*)(ws + OFF_LABELS);
    int* hist             = (int*)(ws + OFF_HIST);
    int* cnt              = (int*)(ws + OFF_CNT);
    float* sums           = (float*)(ws + OFF_SUMS);
    int* ccnt             = (int*)(ws + OFF_CCNT);
    int* thresh           = (int*)(ws + OFF_THRESH);
    float* cval           = (float*)(ws + OFF_CVAL);
    int* cidx             = (int*)(ws + OFF_CIDX);
    float* out            = (float*)d_out;

    hipMemsetAsync(ws + OFF_ZERO, 0, ZERO_BYTES, stream);
    hipMemsetAsync(out, 0, sizeof(float), stream);

    k_stream<<<dim3(V_ / 1024, B_), 256, 0, stream>>>(proba, y, weights, labels, hist, cnt);
    k_sums<<<512, 256, 0, stream>>>(emb, labels, sums);
    k_scan<<<B_, 256, 0, stream>>>(hist, thresh);
    k_collect<<<dim3(V_ / 1024, B_), 256, 0, stream>>>(weights, thresh, ccnt, cval, cidx);
    k_final<<<B_, 256, 0, stream>>>(emb, labels, sums, cnt, ccnt, cval, cidx, out);
}